// Round 5
// baseline (59.486 us; speedup 1.0000x reference)
//
#include <hip/hip_runtime.h>
#include <math.h>

// Problem: P=2, S=2, C=64, F=64, B=64
//   scores[p,s,c,d] = sum_{f,f2} dbfc[p,s,c,f,d,f2]      (268 MB streaming reduction)
//   weights = softmax(scores, axis=d)                     (fused into kernel B prologue)
//   v[b,ps,c,f1] = sum_f0 X[b,ps,c,f0] * wV[f1,f0]
//   out[c, b, ps*64+f1] = sum_d weights[ps,c,d] * v[b,ps,d,f1]

// clang native vector type — __builtin_nontemporal_load requires this
// (HIP_vector_type float4 is a struct and is rejected).
typedef float floatx4 __attribute__((ext_vector_type(4)));

// ---------------------------------------------------------------------------
// Kernel A: 1024 blocks x 256 threads. Block = 1/4 of a (p,s,c) slab
// (256 KB contiguous). Each lane reads 32 B (2 consecutive float4) per step:
// wave covers 2 KB contiguous per issue-pair -> coarser, fewer DRAM streams
// than the round-4 shape (1 KB chunks strided 4 KB from 8192 streams).
// d-mapping: j = i*512 + 2t  ->  d = (t>>3) + 32*(i&1): two parity
// accumulator pairs; 8-lane shfl reduce; 64 partial sums stored per block.
// ---------------------------------------------------------------------------
__global__ __launch_bounds__(256) void scores_partial_kernel(
    const float* __restrict__ dbfc, float* __restrict__ partials)
{
    const int bid   = blockIdx.x;         // 0..1023
    const int slab  = bid >> 2;           // (ps*64 + c)
    const int chunk = bid & 3;
    const int t     = threadIdx.x;        // 0..255

    const floatx4* src = reinterpret_cast<const floatx4*>(dbfc)
                       + (size_t)bid * 16384 + 2 * t;

    floatx4 e0 = (floatx4)0.f, e1 = (floatx4)0.f;   // i even: d = t>>3
    floatx4 o0 = (floatx4)0.f, o1 = (floatx4)0.f;   // i odd : d = (t>>3)+32
#pragma unroll 4
    for (int i = 0; i < 32; ++i) {
        floatx4 v0 = __builtin_nontemporal_load(&src[i * 512 + 0]);
        floatx4 v1 = __builtin_nontemporal_load(&src[i * 512 + 1]);
        if (i & 1) { o0 += v0; o1 += v1; }
        else       { e0 += v0; e1 += v1; }
    }
    floatx4 es = e0 + e1, os = o0 + o1;
    float se = (es.x + es.y) + (es.z + es.w);
    float so = (os.x + os.y) + (os.z + os.w);
    // reduce across the 8 lanes sharing t>>3 (groups never cross waves)
#pragma unroll
    for (int m = 1; m < 8; m <<= 1) {
        se += __shfl_xor(se, m, 64);
        so += __shfl_xor(so, m, 64);
    }
    if ((t & 7) == 0) {
        float* dst = partials + (size_t)chunk * 16384 + slab * 64;
        dst[(t >> 3)]      = se;
        dst[(t >> 3) + 32] = so;
    }
}

// ---------------------------------------------------------------------------
// Kernel B: one block per (ps, b). Stages X-slab / wV in LDS, reduces the 4
// score partials into Ws while staging, softmaxes the 64 rows (4 thr/row),
// computes v with 4x4 register tiles, transposes via LDS, then weights @ v.
// LDS rows stride 68 floats: 16B-aligned, conflict-free for both patterns.
// ---------------------------------------------------------------------------
__global__ __launch_bounds__(256) void attn_out_kernel(
    const float* __restrict__ X, const float* __restrict__ wV,
    const float* __restrict__ partials, float* __restrict__ out)
{
    const int blk = blockIdx.x;   // 0..255
    const int ps  = blk >> 6;     // 0..3
    const int b   = blk & 63;     // 0..63
    const int t   = threadIdx.x;  // 0..255
    const int tc  = t >> 4;       // 0..15
    const int tf  = t & 15;       // 0..15

    __shared__ float Xs [64][68];   // X[b, ps, c, f0]
    __shared__ float wVs[64][68];   // wV[f1][f0]
    __shared__ float Ws [64][68];   // summed scores -> softmaxed weights [c][d]
    __shared__ float VsT[64][68];   // v transposed: [f1][c]

    const float4* xsrc = reinterpret_cast<const float4*>(X + (size_t)b * 16384 + ps * 4096);
    const float4* wsrc = reinterpret_cast<const float4*>(wV);
    const float4* psrc = reinterpret_cast<const float4*>(partials);
#pragma unroll
    for (int idx = t; idx < 1024; idx += 256) {
        int r = idx >> 4, jq = idx & 15, j = jq * 4;
        *reinterpret_cast<float4*>(&Xs [r][j]) = xsrc[idx];
        *reinterpret_cast<float4*>(&wVs[r][j]) = wsrc[idx];
        // sum the 4 chunk partials for (c=r, d=j..j+3)
        float4 s = make_float4(0.f, 0.f, 0.f, 0.f);
#pragma unroll
        for (int k = 0; k < 4; ++k) {
            float4 p = psrc[k * 4096 + (ps * 64 + r) * 16 + jq];
            s.x += p.x; s.y += p.y; s.z += p.z; s.w += p.w;
        }
        *reinterpret_cast<float4*>(&Ws [r][j]) = s;
    }
    __syncthreads();

    // v: acc[ci][fi] = sum_f0 Xs[4tc+ci][f0] * wVs[tf+16fi][f0]
    float acc[4][4] = {};
    for (int f0 = 0; f0 < 64; f0 += 4) {
        float4 xa[4], wv[4];
#pragma unroll
        for (int ci = 0; ci < 4; ++ci)
            xa[ci] = *reinterpret_cast<const float4*>(&Xs[4 * tc + ci][f0]);
#pragma unroll
        for (int fi = 0; fi < 4; ++fi)
            wv[fi] = *reinterpret_cast<const float4*>(&wVs[tf + 16 * fi][f0]);
#pragma unroll
        for (int ci = 0; ci < 4; ++ci)
#pragma unroll
            for (int fi = 0; fi < 4; ++fi)
                acc[ci][fi] += xa[ci].x * wv[fi].x + xa[ci].y * wv[fi].y
                             + xa[ci].z * wv[fi].z + xa[ci].w * wv[fi].w;
    }

    // softmax over d for each of the 64 rows of Ws; 4 threads per row
    {
        const int row = t >> 2, q = (t & 3) * 16;
        float e[16];
        float mx = -INFINITY;
#pragma unroll
        for (int i = 0; i < 16; ++i) mx = fmaxf(mx, Ws[row][q + i]);
        mx = fmaxf(mx, __shfl_xor(mx, 1, 64));
        mx = fmaxf(mx, __shfl_xor(mx, 2, 64));
        float sum = 0.f;
#pragma unroll
        for (int i = 0; i < 16; ++i) { e[i] = expf(Ws[row][q + i] - mx); sum += e[i]; }
        sum += __shfl_xor(sum, 1, 64);
        sum += __shfl_xor(sum, 2, 64);
        const float rinv = 1.0f / sum;
#pragma unroll
        for (int i = 0; i < 16; ++i) Ws[row][q + i] = e[i] * rinv;
    }

    // v -> LDS transposed
#pragma unroll
    for (int ci = 0; ci < 4; ++ci)
#pragma unroll
        for (int fi = 0; fi < 4; ++fi)
            VsT[tf + 16 * fi][4 * tc + ci] = acc[ci][fi];
    __syncthreads();

    // out: o[ci][fi] = sum_d Ws[4tc+ci][d] * VsT[tf+16fi][d]
    float o[4][4] = {};
    for (int d = 0; d < 64; d += 4) {
        float4 wa[4], va[4];
#pragma unroll
        for (int ci = 0; ci < 4; ++ci)
            wa[ci] = *reinterpret_cast<const float4*>(&Ws[4 * tc + ci][d]);
#pragma unroll
        for (int fi = 0; fi < 4; ++fi)
            va[fi] = *reinterpret_cast<const float4*>(&VsT[tf + 16 * fi][d]);
#pragma unroll
        for (int ci = 0; ci < 4; ++ci)
#pragma unroll
            for (int fi = 0; fi < 4; ++fi)
                o[ci][fi] += wa[ci].x * va[fi].x + wa[ci].y * va[fi].y
                           + wa[ci].z * va[fi].z + wa[ci].w * va[fi].w;
    }

    // out[c, b, ps*64 + f1],  c = 4tc+ci,  f1 = tf+16fi
#pragma unroll
    for (int ci = 0; ci < 4; ++ci) {
        const int c = 4 * tc + ci;
        float* orow = out + ((size_t)c * 64 + b) * 256 + ps * 64;
#pragma unroll
        for (int fi = 0; fi < 4; ++fi)
            orow[tf + 16 * fi] = o[ci][fi];
    }
}

extern "C" void kernel_launch(void* const* d_in, const int* in_sizes, int n_in,
                              void* d_out, int out_size, void* d_ws, size_t ws_size,
                              hipStream_t stream)
{
    const float* X    = (const float*)d_in[0];  // [64, 16384]
    const float* dbfc = (const float*)d_in[1];  // [2,2,64,64,64,64]
    const float* wV   = (const float*)d_in[2];  // [64, 64]
    float* out        = (float*)d_out;          // [64, 64, 256]
    float* partials   = (float*)d_ws;           // [4][256][64] = 256 KB scratch

    scores_partial_kernel<<<1024, 256, 0, stream>>>(dbfc, partials);
    attn_out_kernel<<<256, 256, 0, stream>>>(X, wV, partials, out);
}